// Round 1
// baseline (935.877 us; speedup 1.0000x reference)
//
#include <hip/hip_runtime.h>
#include <math.h>

#define BB 4
#define NTOK 1024
#define DIMD 512
#define HH 8
#define DH 64
#define INNER 512
#define BH (BB*HH)          // 32
#define ROWS (BB*NTOK)      // 4096
#define SCALE 0.125f
#define INV_TEMP 10.0f

// ---------------------------------------------------------------------------
// Generic fp32 tiled GEMM: C[M,N] = A[M,K](rm) * W[K,N](rm) + bias
// 64x64 tile, BK=16, 256 threads, 4x4 per thread.
// mode 0: store row-major (ld = Ncols). mode 1: store into [B,H,N,DH] split-head layout.
// ---------------------------------------------------------------------------
__global__ __launch_bounds__(256) void gemm_proj(
    const float* __restrict__ A, const float* __restrict__ W,
    const float* __restrict__ bias, float* __restrict__ out,
    int Kdim, int Ncols, int mode)
{
    __shared__ float As[16][68];   // [k][m], pad 68: 4kk+r spans banks, 2-way max
    __shared__ float Bs[16][64];   // [k][n]
    const int tid = threadIdx.x;
    const int tx = tid & 15, ty = tid >> 4;
    const int rowBase = blockIdx.y * 64;
    const int colBase = blockIdx.x * 64;

    const int kk0 = tid & 15, ar = tid >> 4;   // A loader
    const int bn = tid & 63, bk = tid >> 6;    // W loader

    float acc[4][4] = {};
    for (int k0 = 0; k0 < Kdim; k0 += 16) {
        #pragma unroll
        for (int it = 0; it < 4; ++it) {
            int r = ar + it * 16;
            As[kk0][r] = A[(size_t)(rowBase + r) * Kdim + k0 + kk0];
        }
        #pragma unroll
        for (int it = 0; it < 4; ++it) {
            int k = bk + it * 4;
            Bs[k][bn] = W[(size_t)(k0 + k) * Ncols + colBase + bn];
        }
        __syncthreads();
        #pragma unroll
        for (int kk = 0; kk < 16; ++kk) {
            float a[4], b[4];
            #pragma unroll
            for (int i = 0; i < 4; ++i) a[i] = As[kk][ty * 4 + i];
            #pragma unroll
            for (int j = 0; j < 4; ++j) b[j] = Bs[kk][tx * 4 + j];
            #pragma unroll
            for (int i = 0; i < 4; ++i)
                #pragma unroll
                for (int j = 0; j < 4; ++j)
                    acc[i][j] += a[i] * b[j];
        }
        __syncthreads();
    }
    #pragma unroll
    for (int i = 0; i < 4; ++i) {
        int r = rowBase + ty * 4 + i;
        #pragma unroll
        for (int j = 0; j < 4; ++j) {
            int c = colBase + tx * 4 + j;
            float v = acc[i][j] + bias[c];
            if (mode == 0) {
                out[(size_t)r * Ncols + c] = v;
            } else {
                int b = r >> 10, n = r & 1023, h = c >> 6, d = c & 63;
                out[(((size_t)b * HH + h) * NTOK + n) * DH + d] = v;
            }
        }
    }
}

// ---------------------------------------------------------------------------
// Scores: S[bh][i][j] = sum_d Q[bh][i][d]*K[bh][j][d], written into attn region
// ---------------------------------------------------------------------------
__global__ __launch_bounds__(256) void scores_kernel(
    const float* __restrict__ q, const float* __restrict__ k,
    float* __restrict__ attn)
{
    __shared__ float As[16][68];   // [d][i]
    __shared__ float Bs[16][68];   // [d][j]
    const int tid = threadIdx.x;
    const int tx = tid & 15, ty = tid >> 4;
    const int bh = blockIdx.z;
    const int iBase = blockIdx.y * 64;
    const int jBase = blockIdx.x * 64;
    const float* Q = q + (size_t)bh * NTOK * DH;
    const float* K = k + (size_t)bh * NTOK * DH;
    const int dd = tid & 15, rr = tid >> 4;

    float acc[4][4] = {};
    for (int d0 = 0; d0 < DH; d0 += 16) {
        #pragma unroll
        for (int it = 0; it < 4; ++it) {
            int r = rr + it * 16;
            As[dd][r] = Q[(size_t)(iBase + r) * DH + d0 + dd];
            Bs[dd][r] = K[(size_t)(jBase + r) * DH + d0 + dd];
        }
        __syncthreads();
        #pragma unroll
        for (int kk = 0; kk < 16; ++kk) {
            float a[4], b[4];
            #pragma unroll
            for (int i = 0; i < 4; ++i) a[i] = As[kk][ty * 4 + i];
            #pragma unroll
            for (int j = 0; j < 4; ++j) b[j] = Bs[kk][tx * 4 + j];
            #pragma unroll
            for (int i = 0; i < 4; ++i)
                #pragma unroll
                for (int j = 0; j < 4; ++j)
                    acc[i][j] += a[i] * b[j];
        }
        __syncthreads();
    }
    float* outp = attn + (size_t)bh * NTOK * NTOK;
    #pragma unroll
    for (int i = 0; i < 4; ++i)
        #pragma unroll
        for (int j = 0; j < 4; ++j)
            outp[(size_t)(iBase + ty * 4 + i) * NTOK + jBase + tx * 4 + j] = acc[i][j];
}

// ---------------------------------------------------------------------------
// q/k row norms: one 64-thread block per (bh,n) row
// ---------------------------------------------------------------------------
__global__ __launch_bounds__(64) void norm_kernel(
    const float* __restrict__ q, const float* __restrict__ k,
    float* __restrict__ qn, float* __restrict__ kn)
{
    const int row = blockIdx.x;
    const float* src = blockIdx.y ? k : q;
    float* dst = blockIdx.y ? kn : qn;
    float v = src[(size_t)row * DH + threadIdx.x];
    float s = v * v;
    #pragma unroll
    for (int off = 32; off; off >>= 1) s += __shfl_down(s, off);
    if (threadIdx.x == 0) dst[row] = sqrtf(s);
}

// ---------------------------------------------------------------------------
// Fused per-row pass: DCL terms + masked softmax (in place on attn region)
// ---------------------------------------------------------------------------
__device__ __forceinline__ float block_sum(float v, float* sh)
{
    #pragma unroll
    for (int off = 32; off; off >>= 1) v += __shfl_down(v, off);
    __syncthreads();
    if ((threadIdx.x & 63) == 0) sh[threadIdx.x >> 6] = v;
    __syncthreads();
    return sh[0] + sh[1] + sh[2] + sh[3];
}

__device__ __forceinline__ float block_max(float v, float* sh)
{
    #pragma unroll
    for (int off = 32; off; off >>= 1) v = fmaxf(v, __shfl_down(v, off));
    __syncthreads();
    if ((threadIdx.x & 63) == 0) sh[threadIdx.x >> 6] = v;
    __syncthreads();
    return fmaxf(fmaxf(sh[0], sh[1]), fmaxf(sh[2], sh[3]));
}

__global__ __launch_bounds__(256) void row_kernel(
    float* __restrict__ attn, const int* __restrict__ mask,
    const float* __restrict__ qn, const float* __restrict__ kn,
    float* __restrict__ acc)
{
    __shared__ float sh[4];
    const int row = blockIdx.x;            // bh*1024 + i
    const int bh = row >> 10, i = row & 1023;
    const int b = bh >> 3, h = bh & 7;
    const int t = threadIdx.x;
    float* srow = attn + (size_t)row * NTOK;
    const int* mrow = mask + ((size_t)b * NTOK + i) * NTOK;
    const float* knrow = kn + (size_t)bh * NTOK;
    const float qni = qn[row];

    float s[4], z[4];
    int m[4];
    float pos = 0.f, alls = 0.f, zmax = -1e30f, reg = 0.f;
    #pragma unroll
    for (int u = 0; u < 4; ++u) {
        int j = t + u * 256;
        s[u] = srow[j];
        m[u] = mrow[j];
        float cosv = s[u] / (qni * knrow[j]);
        float e = __expf(cosv * INV_TEMP);
        alls += e;
        if (m[u]) pos += e;
        reg += (float)m[u];
        if (j == i) reg -= 2.0f * (float)m[u];   // diagonal: |m_ii-1| handled via +1 later
        z[u] = (m[u] ? s[u] : -1.0e9f) * SCALE;
        zmax = fmaxf(zmax, z[u]);
    }
    float post = block_sum(pos, sh);
    float allt = block_sum(alls, sh);
    float regt = block_sum(reg, sh);
    float zmx  = block_max(zmax, sh);

    float ex[4], esum = 0.f;
    #pragma unroll
    for (int u = 0; u < 4; ++u) { ex[u] = __expf(z[u] - zmx); esum += ex[u]; }
    float est = block_sum(esum, sh);
    float inv = 1.0f / est;
    #pragma unroll
    for (int u = 0; u < 4; ++u) srow[t + u * 256] = ex[u] * inv;

    if (t == 0) {
        atomicAdd(&acc[0], logf(allt) - logf(post));   // clustering for this (b,h,i)
        if (h == 0) atomicAdd(&acc[1], regt + 1.0f);   // |am - I| row sum (m_ii==1 or 0 both handled)
    }
}

__global__ void finalize_kernel(const float* __restrict__ acc, float* __restrict__ dcl)
{
    dcl[0] = acc[0] * (1.0f / (float)(BB * HH * NTOK))
           + 0.3f * acc[1] * (1.0f / ((float)NTOK * (float)(NTOK - 1) * (float)BB));
}

// ---------------------------------------------------------------------------
// attn @ V -> ctx [b, n, h*DH+d]
// ---------------------------------------------------------------------------
__global__ __launch_bounds__(256) void av_kernel(
    const float* __restrict__ attn, const float* __restrict__ v,
    float* __restrict__ ctx)
{
    __shared__ float As[16][68];
    __shared__ float Bs[16][64];
    const int tid = threadIdx.x;
    const int tx = tid & 15, ty = tid >> 4;
    const int bh = blockIdx.z;
    const int b = bh >> 3, h = bh & 7;
    const int iBase = blockIdx.y * 64;
    const float* A = attn + (size_t)bh * NTOK * NTOK;
    const float* V = v + (size_t)bh * NTOK * DH;
    const int kk0 = tid & 15, ar = tid >> 4;
    const int bn = tid & 63, bkr = tid >> 6;

    float acc[4][4] = {};
    for (int k0 = 0; k0 < NTOK; k0 += 16) {
        #pragma unroll
        for (int it = 0; it < 4; ++it) {
            int r = ar + it * 16;
            As[kk0][r] = A[(size_t)(iBase + r) * NTOK + k0 + kk0];
        }
        #pragma unroll
        for (int it = 0; it < 4; ++it) {
            int kr = bkr + it * 4;
            Bs[kr][bn] = V[(size_t)(k0 + kr) * DH + bn];
        }
        __syncthreads();
        #pragma unroll
        for (int kk = 0; kk < 16; ++kk) {
            float a[4], bv[4];
            #pragma unroll
            for (int i = 0; i < 4; ++i) a[i] = As[kk][ty * 4 + i];
            #pragma unroll
            for (int j = 0; j < 4; ++j) bv[j] = Bs[kk][tx * 4 + j];
            #pragma unroll
            for (int i = 0; i < 4; ++i)
                #pragma unroll
                for (int j = 0; j < 4; ++j)
                    acc[i][j] += a[i] * bv[j];
        }
        __syncthreads();
    }
    #pragma unroll
    for (int i = 0; i < 4; ++i) {
        int ii = iBase + ty * 4 + i;
        #pragma unroll
        for (int j = 0; j < 4; ++j) {
            int d = tx * 4 + j;
            ctx[(size_t)(b * NTOK + ii) * INNER + h * DH + d] = acc[i][j];
        }
    }
}

// ---------------------------------------------------------------------------
extern "C" void kernel_launch(void* const* d_in, const int* in_sizes, int n_in,
                              void* d_out, int out_size, void* d_ws, size_t ws_size,
                              hipStream_t stream)
{
    const float* x  = (const float*)d_in[0];
    const int* mask = (const int*)d_in[1];
    const float* Wq = (const float*)d_in[2];
    const float* bq = (const float*)d_in[3];
    const float* Wk = (const float*)d_in[4];
    const float* bk = (const float*)d_in[5];
    const float* Wv = (const float*)d_in[6];
    const float* bv = (const float*)d_in[7];
    const float* Wo = (const float*)d_in[8];
    const float* bo = (const float*)d_in[9];

    float* out  = (float*)d_out;                         // [4096, 512]
    float* attn = out + (size_t)ROWS * DIMD;             // [32, 1024, 1024]
    float* dcl  = attn + (size_t)BH * NTOK * NTOK;       // scalar

    float* ws  = (float*)d_ws;
    float* q   = ws;                                     // [B,H,N,DH]
    float* k   = q + (size_t)ROWS * INNER;
    float* v   = k + (size_t)ROWS * INNER;
    float* ctx = v + (size_t)ROWS * INNER;               // [B,N,INNER]
    float* qn  = ctx + (size_t)ROWS * INNER;             // [BH,N]
    float* kn  = qn + BH * NTOK;
    float* acc = kn + BH * NTOK;                         // 2 floats

    hipMemsetAsync(acc, 0, 2 * sizeof(float), stream);

    dim3 blk(256);
    gemm_proj<<<dim3(8, 64), blk, 0, stream>>>(x, Wq, bq, q, DIMD, INNER, 1);
    gemm_proj<<<dim3(8, 64), blk, 0, stream>>>(x, Wk, bk, k, DIMD, INNER, 1);
    gemm_proj<<<dim3(8, 64), blk, 0, stream>>>(x, Wv, bv, v, DIMD, INNER, 1);
    norm_kernel<<<dim3(BH * NTOK, 2), dim3(64), 0, stream>>>(q, k, qn, kn);
    scores_kernel<<<dim3(16, 16, 32), blk, 0, stream>>>(q, k, attn);
    row_kernel<<<dim3(BH * NTOK), blk, 0, stream>>>(attn, mask, qn, kn, acc);
    finalize_kernel<<<1, 1, 0, stream>>>(acc, dcl);
    av_kernel<<<dim3(1, 16, 32), blk, 0, stream>>>(attn, v, ctx);
    gemm_proj<<<dim3(8, 64), blk, 0, stream>>>(ctx, Wo, bo, out, INNER, DIMD, 0);
}

// Round 2
// 550.655 us; speedup vs baseline: 1.6996x; 1.6996x over previous
//
#include <hip/hip_runtime.h>
#include <math.h>

#define BB 4
#define NTOK 1024
#define DIMD 512
#define HH 8
#define DH 64
#define INNER 512
#define BH (BB*HH)          // 32
#define ROWS (BB*NTOK)      // 4096
#define SCALE 0.125f
#define INV_TEMP 10.0f

// ---------------------------------------------------------------------------
// Generic fp32 tiled GEMM: C[M,N] = A[M,K](rm) * W[K,N](rm) + bias
// 64x64 tile, BK=16, 256 threads, 4x4 per thread.
// mode 0: store row-major (ld = Ncols). mode 1: store into [B,H,N,DH] split-head layout.
// ---------------------------------------------------------------------------
__global__ __launch_bounds__(256) void gemm_proj(
    const float* __restrict__ A, const float* __restrict__ W,
    const float* __restrict__ bias, float* __restrict__ out,
    int Kdim, int Ncols, int mode)
{
    __shared__ float As[16][68];
    __shared__ float Bs[16][64];
    const int tid = threadIdx.x;
    const int tx = tid & 15, ty = tid >> 4;
    const int rowBase = blockIdx.y * 64;
    const int colBase = blockIdx.x * 64;

    const int kk0 = tid & 15, ar = tid >> 4;   // A loader
    const int bn = tid & 63, bk = tid >> 6;    // W loader

    float acc[4][4] = {};
    for (int k0 = 0; k0 < Kdim; k0 += 16) {
        #pragma unroll
        for (int it = 0; it < 4; ++it) {
            int r = ar + it * 16;
            As[kk0][r] = A[(size_t)(rowBase + r) * Kdim + k0 + kk0];
        }
        #pragma unroll
        for (int it = 0; it < 4; ++it) {
            int k = bk + it * 4;
            Bs[k][bn] = W[(size_t)(k0 + k) * Ncols + colBase + bn];
        }
        __syncthreads();
        #pragma unroll
        for (int kk = 0; kk < 16; ++kk) {
            float a[4], b[4];
            #pragma unroll
            for (int i = 0; i < 4; ++i) a[i] = As[kk][ty * 4 + i];
            #pragma unroll
            for (int j = 0; j < 4; ++j) b[j] = Bs[kk][tx * 4 + j];
            #pragma unroll
            for (int i = 0; i < 4; ++i)
                #pragma unroll
                for (int j = 0; j < 4; ++j)
                    acc[i][j] += a[i] * b[j];
        }
        __syncthreads();
    }
    #pragma unroll
    for (int i = 0; i < 4; ++i) {
        int r = rowBase + ty * 4 + i;
        #pragma unroll
        for (int j = 0; j < 4; ++j) {
            int c = colBase + tx * 4 + j;
            float v = acc[i][j] + bias[c];
            if (mode == 0) {
                out[(size_t)r * Ncols + c] = v;
            } else {
                int b = r >> 10, n = r & 1023, h = c >> 6, d = c & 63;
                out[(((size_t)b * HH + h) * NTOK + n) * DH + d] = v;
            }
        }
    }
}

// ---------------------------------------------------------------------------
// Scores: S[bh][i][j] = sum_d Q[bh][i][d]*K[bh][j][d], written into attn region
// ---------------------------------------------------------------------------
__global__ __launch_bounds__(256) void scores_kernel(
    const float* __restrict__ q, const float* __restrict__ k,
    float* __restrict__ attn)
{
    __shared__ float As[16][68];   // [d][i]
    __shared__ float Bs[16][68];   // [d][j]
    const int tid = threadIdx.x;
    const int tx = tid & 15, ty = tid >> 4;
    const int bh = blockIdx.z;
    const int iBase = blockIdx.y * 64;
    const int jBase = blockIdx.x * 64;
    const float* Q = q + (size_t)bh * NTOK * DH;
    const float* K = k + (size_t)bh * NTOK * DH;
    const int dd = tid & 15, rr = tid >> 4;

    float acc[4][4] = {};
    for (int d0 = 0; d0 < DH; d0 += 16) {
        #pragma unroll
        for (int it = 0; it < 4; ++it) {
            int r = rr + it * 16;
            As[dd][r] = Q[(size_t)(iBase + r) * DH + d0 + dd];
            Bs[dd][r] = K[(size_t)(jBase + r) * DH + d0 + dd];
        }
        __syncthreads();
        #pragma unroll
        for (int kk = 0; kk < 16; ++kk) {
            float a[4], b[4];
            #pragma unroll
            for (int i = 0; i < 4; ++i) a[i] = As[kk][ty * 4 + i];
            #pragma unroll
            for (int j = 0; j < 4; ++j) b[j] = Bs[kk][tx * 4 + j];
            #pragma unroll
            for (int i = 0; i < 4; ++i)
                #pragma unroll
                for (int j = 0; j < 4; ++j)
                    acc[i][j] += a[i] * b[j];
        }
        __syncthreads();
    }
    float* outp = attn + (size_t)bh * NTOK * NTOK;
    #pragma unroll
    for (int i = 0; i < 4; ++i)
        #pragma unroll
        for (int j = 0; j < 4; ++j)
            outp[(size_t)(iBase + ty * 4 + i) * NTOK + jBase + tx * 4 + j] = acc[i][j];
}

// ---------------------------------------------------------------------------
// q/k row norms: one 64-thread block per (bh,n) row
// ---------------------------------------------------------------------------
__global__ __launch_bounds__(64) void norm_kernel(
    const float* __restrict__ q, const float* __restrict__ k,
    float* __restrict__ qn, float* __restrict__ kn)
{
    const int row = blockIdx.x;
    const float* src = blockIdx.y ? k : q;
    float* dst = blockIdx.y ? kn : qn;
    float v = src[(size_t)row * DH + threadIdx.x];
    float s = v * v;
    #pragma unroll
    for (int off = 32; off; off >>= 1) s += __shfl_down(s, off);
    if (threadIdx.x == 0) dst[row] = sqrtf(s);
}

// ---------------------------------------------------------------------------
// Block reduction helpers (256 threads)
// ---------------------------------------------------------------------------
__device__ __forceinline__ float block_sum(float v, float* sh)
{
    #pragma unroll
    for (int off = 32; off; off >>= 1) v += __shfl_down(v, off);
    __syncthreads();
    if ((threadIdx.x & 63) == 0) sh[threadIdx.x >> 6] = v;
    __syncthreads();
    return sh[0] + sh[1] + sh[2] + sh[3];
}

__device__ __forceinline__ float block_max(float v, float* sh)
{
    #pragma unroll
    for (int off = 32; off; off >>= 1) v = fmaxf(v, __shfl_down(v, off));
    __syncthreads();
    if ((threadIdx.x & 63) == 0) sh[threadIdx.x >> 6] = v;
    __syncthreads();
    return fmaxf(fmaxf(sh[0], sh[1]), fmaxf(sh[2], sh[3]));
}

// ---------------------------------------------------------------------------
// Fused per-row pass: DCL terms + masked softmax (in place on attn region).
// NO atomics: per-row partials go to cl[row] / rg[b*N+i] (contention-free),
// reduced by finalize_kernel. (R0 post-mortem: 32768 same-address atomicAdds
// serialized at the TCC = 475us.)
// ---------------------------------------------------------------------------
__global__ __launch_bounds__(256) void row_kernel(
    float* __restrict__ attn, const int* __restrict__ mask,
    const float* __restrict__ qn, const float* __restrict__ kn,
    float* __restrict__ cl, float* __restrict__ rg)
{
    __shared__ float sh[4];
    const int row = blockIdx.x;            // bh*1024 + i
    const int bh = row >> 10, i = row & 1023;
    const int b = bh >> 3, h = bh & 7;
    const int t = threadIdx.x;
    float* srow = attn + (size_t)row * NTOK;
    const int* mrow = mask + ((size_t)b * NTOK + i) * NTOK;
    const float* knrow = kn + (size_t)bh * NTOK;
    const float qni = qn[row];

    float s[4], z[4];
    int m[4];
    float pos = 0.f, alls = 0.f, zmax = -1e30f, reg = 0.f;
    #pragma unroll
    for (int u = 0; u < 4; ++u) {
        int j = t + u * 256;
        s[u] = srow[j];
        m[u] = mrow[j];
        float cosv = s[u] / (qni * knrow[j]);
        float e = __expf(cosv * INV_TEMP);
        alls += e;
        if (m[u]) pos += e;
        reg += (float)m[u];
        if (j == i) reg -= 2.0f * (float)m[u];
        z[u] = (m[u] ? s[u] : -1.0e9f) * SCALE;
        zmax = fmaxf(zmax, z[u]);
    }
    float post = block_sum(pos, sh);
    float allt = block_sum(alls, sh);
    float regt = block_sum(reg, sh);
    float zmx  = block_max(zmax, sh);

    float ex[4], esum = 0.f;
    #pragma unroll
    for (int u = 0; u < 4; ++u) { ex[u] = __expf(z[u] - zmx); esum += ex[u]; }
    float est = block_sum(esum, sh);
    float inv = 1.0f / est;
    #pragma unroll
    for (int u = 0; u < 4; ++u) srow[t + u * 256] = ex[u] * inv;

    if (t == 0) {
        cl[row] = logf(allt) - logf(post);
        if (h == 0) rg[b * NTOK + i] = regt + 1.0f;
    }
}

// ---------------------------------------------------------------------------
// Single-block deterministic reduction of the DCL partials
// ---------------------------------------------------------------------------
__global__ __launch_bounds__(256) void finalize_kernel(
    const float* __restrict__ cl, const float* __restrict__ rg,
    float* __restrict__ dcl)
{
    __shared__ float sh[4];
    float s1 = 0.f, s2 = 0.f;
    for (int idx = threadIdx.x; idx < BH * NTOK; idx += 256) s1 += cl[idx];
    for (int idx = threadIdx.x; idx < BB * NTOK; idx += 256) s2 += rg[idx];
    s1 = block_sum(s1, sh);
    s2 = block_sum(s2, sh);
    if (threadIdx.x == 0) {
        dcl[0] = s1 * (1.0f / (float)(BB * HH * NTOK))
               + 0.3f * s2 * (1.0f / ((float)NTOK * (float)(NTOK - 1) * (float)BB));
    }
}

// ---------------------------------------------------------------------------
// attn @ V -> ctx [b, n, h*DH+d]
// ---------------------------------------------------------------------------
__global__ __launch_bounds__(256) void av_kernel(
    const float* __restrict__ attn, const float* __restrict__ v,
    float* __restrict__ ctx)
{
    __shared__ float As[16][68];
    __shared__ float Bs[16][64];
    const int tid = threadIdx.x;
    const int tx = tid & 15, ty = tid >> 4;
    const int bh = blockIdx.z;
    const int b = bh >> 3, h = bh & 7;
    const int iBase = blockIdx.y * 64;
    const float* A = attn + (size_t)bh * NTOK * NTOK;
    const float* V = v + (size_t)bh * NTOK * DH;
    const int kk0 = tid & 15, ar = tid >> 4;
    const int bn = tid & 63, bkr = tid >> 6;

    float acc[4][4] = {};
    for (int k0 = 0; k0 < NTOK; k0 += 16) {
        #pragma unroll
        for (int it = 0; it < 4; ++it) {
            int r = ar + it * 16;
            As[kk0][r] = A[(size_t)(iBase + r) * NTOK + k0 + kk0];
        }
        #pragma unroll
        for (int it = 0; it < 4; ++it) {
            int kr = bkr + it * 4;
            Bs[kr][bn] = V[(size_t)(k0 + kr) * DH + bn];
        }
        __syncthreads();
        #pragma unroll
        for (int kk = 0; kk < 16; ++kk) {
            float a[4], bv[4];
            #pragma unroll
            for (int i = 0; i < 4; ++i) a[i] = As[kk][ty * 4 + i];
            #pragma unroll
            for (int j = 0; j < 4; ++j) bv[j] = Bs[kk][tx * 4 + j];
            #pragma unroll
            for (int i = 0; i < 4; ++i)
                #pragma unroll
                for (int j = 0; j < 4; ++j)
                    acc[i][j] += a[i] * bv[j];
        }
        __syncthreads();
    }
    #pragma unroll
    for (int i = 0; i < 4; ++i) {
        int ii = iBase + ty * 4 + i;
        #pragma unroll
        for (int j = 0; j < 4; ++j) {
            int d = tx * 4 + j;
            ctx[(size_t)(b * NTOK + ii) * INNER + h * DH + d] = acc[i][j];
        }
    }
}

// ---------------------------------------------------------------------------
extern "C" void kernel_launch(void* const* d_in, const int* in_sizes, int n_in,
                              void* d_out, int out_size, void* d_ws, size_t ws_size,
                              hipStream_t stream)
{
    const float* x  = (const float*)d_in[0];
    const int* mask = (const int*)d_in[1];
    const float* Wq = (const float*)d_in[2];
    const float* bq = (const float*)d_in[3];
    const float* Wk = (const float*)d_in[4];
    const float* bk = (const float*)d_in[5];
    const float* Wv = (const float*)d_in[6];
    const float* bv = (const float*)d_in[7];
    const float* Wo = (const float*)d_in[8];
    const float* bo = (const float*)d_in[9];

    float* out  = (float*)d_out;                         // [4096, 512]
    float* attn = out + (size_t)ROWS * DIMD;             // [32, 1024, 1024]
    float* dcl  = attn + (size_t)BH * NTOK * NTOK;       // scalar

    float* ws  = (float*)d_ws;
    float* q   = ws;                                     // [B,H,N,DH]
    float* k   = q + (size_t)ROWS * INNER;
    float* v   = k + (size_t)ROWS * INNER;
    float* ctx = v + (size_t)ROWS * INNER;               // [B,N,INNER]
    float* qn  = ctx + (size_t)ROWS * INNER;             // [BH,N]
    float* kn  = qn + BH * NTOK;
    float* cl  = kn + BH * NTOK;                         // [BH*NTOK]
    float* rg  = cl + BH * NTOK;                         // [BB*NTOK]

    dim3 blk(256);
    gemm_proj<<<dim3(8, 64), blk, 0, stream>>>(x, Wq, bq, q, DIMD, INNER, 1);
    gemm_proj<<<dim3(8, 64), blk, 0, stream>>>(x, Wk, bk, k, DIMD, INNER, 1);
    gemm_proj<<<dim3(8, 64), blk, 0, stream>>>(x, Wv, bv, v, DIMD, INNER, 1);
    norm_kernel<<<dim3(BH * NTOK, 2), dim3(64), 0, stream>>>(q, k, qn, kn);
    scores_kernel<<<dim3(16, 16, 32), blk, 0, stream>>>(q, k, attn);
    row_kernel<<<dim3(BH * NTOK), blk, 0, stream>>>(attn, mask, qn, kn, cl, rg);
    finalize_kernel<<<1, blk, 0, stream>>>(cl, rg, dcl);
    av_kernel<<<dim3(1, 16, 32), blk, 0, stream>>>(attn, v, ctx);
    gemm_proj<<<dim3(8, 64), blk, 0, stream>>>(ctx, Wo, bo, out, INNER, DIMD, 0);
}

// Round 3
// 340.375 us; speedup vs baseline: 2.7495x; 1.6178x over previous
//
#include <hip/hip_runtime.h>
#include <hip/hip_bf16.h>
#include <math.h>

#define BB 4
#define NTOK 1024
#define DIMD 512
#define HH 8
#define DH 64
#define INNER 512
#define BH (BB*HH)          // 32
#define ROWS (BB*NTOK)      // 4096
#define SCALE 0.125f
#define INV_TEMP 10.0f

typedef __bf16 bf16_t;
using bf16x4 = __attribute__((ext_vector_type(4))) __bf16;
using bf16x8 = __attribute__((ext_vector_type(8))) __bf16;
using f32x4  = __attribute__((ext_vector_type(4))) float;

// ---------------------------------------------------------------------------
// Shared MFMA GEMM core: C[TM,TN] += A[TM,K] * B[TN,K]^T, both bf16 K-fastest.
// 256 threads. Wave grid: WGN = TN/(NT*16) wave-cols; each wave MT*16 x NT*16.
// BK=32 per stage, mfma_f32_16x16x32_bf16.
//   A frag (lane l): A[m = l&15][k = (l>>4)*8 + j]   (16B contiguous)
//   B frag (lane l): B^T[n = l&15][k = (l>>4)*8 + j] (identical pattern)
//   C/D (lane l, reg r): row = (l>>4)*4 + r, col = l&15   [m89/m91 verified]
// ---------------------------------------------------------------------------
template<int TM, int TN, int MT, int NT>
__device__ __forceinline__ void gemm_core(
    const bf16_t* __restrict__ A, int ldA,
    const bf16_t* __restrict__ B, int ldB, int K,
    bf16_t* As, bf16_t* Bs, f32x4 (&acc)[MT][NT])
{
    const int t = threadIdx.x;
    const int w = t >> 6, l = t & 63;
    constexpr int WGN = TN / (NT * 16);
    const int wm = w / WGN, wn = w % WGN;
    const int lrow = l & 15, lk = (l >> 4) * 8;

    for (int k0 = 0; k0 < K; k0 += 32) {
        #pragma unroll
        for (int it = 0; it < TM / 64; ++it) {
            int r = (t >> 2) + it * 64;
            *(uint4*)&As[r * 32 + (t & 3) * 8] =
                *(const uint4*)&A[(size_t)r * ldA + k0 + (t & 3) * 8];
        }
        #pragma unroll
        for (int it = 0; it < TN / 64; ++it) {
            int r = (t >> 2) + it * 64;
            *(uint4*)&Bs[r * 32 + (t & 3) * 8] =
                *(const uint4*)&B[(size_t)r * ldB + k0 + (t & 3) * 8];
        }
        __syncthreads();
        bf16x8 af[MT], bf[NT];
        #pragma unroll
        for (int mt = 0; mt < MT; ++mt)
            af[mt] = *(const bf16x8*)&As[(wm * MT * 16 + mt * 16 + lrow) * 32 + lk];
        #pragma unroll
        for (int nt = 0; nt < NT; ++nt)
            bf[nt] = *(const bf16x8*)&Bs[(wn * NT * 16 + nt * 16 + lrow) * 32 + lk];
        #pragma unroll
        for (int mt = 0; mt < MT; ++mt)
            #pragma unroll
            for (int nt = 0; nt < NT; ++nt)
                acc[mt][nt] = __builtin_amdgcn_mfma_f32_16x16x32_bf16(
                    af[mt], bf[nt], acc[mt][nt], 0, 0, 0);
        __syncthreads();
    }
}

// ---------------------------------------------------------------------------
// Prep: fp32 x -> bf16 xb
// ---------------------------------------------------------------------------
__global__ __launch_bounds__(256) void convert_x(
    const float* __restrict__ x, bf16_t* __restrict__ xb)
{
    int idx = blockIdx.x * 256 + threadIdx.x;
    float4 v = ((const float4*)x)[idx];
    bf16x4 o = { (bf16_t)v.x, (bf16_t)v.y, (bf16_t)v.z, (bf16_t)v.w };
    ((bf16x4*)xb)[idx] = o;
}

// ---------------------------------------------------------------------------
// Prep: W [512c][512o] fp32 -> Wt [512o][512c] bf16 (z picks Wq/Wk/Wv/Wo)
// ---------------------------------------------------------------------------
__global__ __launch_bounds__(256) void transpose_w(
    const float* __restrict__ Wq, const float* __restrict__ Wk,
    const float* __restrict__ Wv, const float* __restrict__ Wo,
    bf16_t* __restrict__ wt)
{
    __shared__ float tile[32][33];
    const int z = blockIdx.z;
    const float* src = (z == 0) ? Wq : (z == 1) ? Wk : (z == 2) ? Wv : Wo;
    bf16_t* dst = wt + (size_t)z * DIMD * INNER;
    const int t = threadIdx.x, tx = t & 31, ty = t >> 5;
    const int rBase = blockIdx.y * 32, cBase = blockIdx.x * 32;
    #pragma unroll
    for (int i = 0; i < 4; ++i)
        tile[ty + i * 8][tx] = src[(size_t)(rBase + ty + i * 8) * INNER + cBase + tx];
    __syncthreads();
    #pragma unroll
    for (int i = 0; i < 4; ++i)
        dst[(size_t)(cBase + ty + i * 8) * DIMD + rBase + tx] = (bf16_t)tile[tx][ty + i * 8];
}

// ---------------------------------------------------------------------------
// QKV projection: xb[4096,512] @ Wt[z]^T + bias -> q/k (split-head), v (transposed)
// ---------------------------------------------------------------------------
__global__ __launch_bounds__(256) void qkv_gemm(
    const bf16_t* __restrict__ xb, const bf16_t* __restrict__ wt,
    const float* __restrict__ bq, const float* __restrict__ bk,
    const float* __restrict__ bv,
    bf16_t* __restrict__ qb, bf16_t* __restrict__ kb, bf16_t* __restrict__ vt)
{
    __shared__ __align__(16) bf16_t As[128 * 32];
    __shared__ __align__(16) bf16_t Bs[128 * 32];
    const int z = blockIdx.z;
    const bf16_t* Bp = wt + (size_t)z * DIMD * INNER;
    const float* bias = (z == 0) ? bq : (z == 1) ? bk : bv;
    const int rowBase = blockIdx.y * 128, colBase = blockIdx.x * 128;

    f32x4 acc[4][4] = {};
    gemm_core<128, 128, 4, 4>(xb + (size_t)rowBase * DIMD, DIMD,
                              Bp + (size_t)colBase * DIMD, DIMD, DIMD,
                              As, Bs, acc);

    const int l = threadIdx.x & 63, w = threadIdx.x >> 6;
    const int wm = w >> 1, wn = w & 1;
    #pragma unroll
    for (int mt = 0; mt < 4; ++mt)
        #pragma unroll
        for (int nt = 0; nt < 4; ++nt)
            #pragma unroll
            for (int r = 0; r < 4; ++r) {
                int grow = rowBase + wm * 64 + mt * 16 + (l >> 4) * 4 + r;
                int gcol = colBase + wn * 64 + nt * 16 + (l & 15);
                float val = acc[mt][nt][r] + bias[gcol];
                int b = grow >> 10, n = grow & 1023, h = gcol >> 6, d = gcol & 63;
                if (z == 0)
                    qb[(((size_t)b * HH + h) * NTOK + n) * DH + d] = (bf16_t)val;
                else if (z == 1)
                    kb[(((size_t)b * HH + h) * NTOK + n) * DH + d] = (bf16_t)val;
                else
                    vt[(((size_t)b * HH + h) * DH + d) * NTOK + n] = (bf16_t)val;
            }
}

// ---------------------------------------------------------------------------
// Scores: qb[bh] @ kb[bh]^T -> fp32 scores into attn region of d_out
// ---------------------------------------------------------------------------
__global__ __launch_bounds__(256) void scores_gemm(
    const bf16_t* __restrict__ qb, const bf16_t* __restrict__ kb,
    float* __restrict__ attnf)
{
    __shared__ __align__(16) bf16_t As[128 * 32];
    __shared__ __align__(16) bf16_t Bs[128 * 32];
    const int bh = blockIdx.z;
    const int rowBase = blockIdx.y * 128, colBase = blockIdx.x * 128;
    const bf16_t* Q = qb + (size_t)bh * NTOK * DH;
    const bf16_t* K = kb + (size_t)bh * NTOK * DH;

    f32x4 acc[4][4] = {};
    gemm_core<128, 128, 4, 4>(Q + (size_t)rowBase * DH, DH,
                              K + (size_t)colBase * DH, DH, DH,
                              As, Bs, acc);

    float* outp = attnf + (size_t)bh * NTOK * NTOK;
    const int l = threadIdx.x & 63, w = threadIdx.x >> 6;
    const int wm = w >> 1, wn = w & 1;
    #pragma unroll
    for (int mt = 0; mt < 4; ++mt)
        #pragma unroll
        for (int nt = 0; nt < 4; ++nt)
            #pragma unroll
            for (int r = 0; r < 4; ++r) {
                int grow = rowBase + wm * 64 + mt * 16 + (l >> 4) * 4 + r;
                int gcol = colBase + wn * 64 + nt * 16 + (l & 15);
                outp[(size_t)grow * NTOK + gcol] = acc[mt][nt][r];
            }
}

// ---------------------------------------------------------------------------
// q/k row norms from bf16 [bh*n][64] rows; 256 thr = 4 rows/block
// ---------------------------------------------------------------------------
__global__ __launch_bounds__(256) void norm_kernel(
    const bf16_t* __restrict__ qb, const bf16_t* __restrict__ kb,
    float* __restrict__ qn, float* __restrict__ kn)
{
    const int row = blockIdx.x * 4 + (threadIdx.x >> 6);
    const int d = threadIdx.x & 63;
    const bf16_t* src = blockIdx.y ? kb : qb;
    float* dst = blockIdx.y ? kn : qn;
    float v = (float)src[(size_t)row * DH + d];
    float s = v * v;
    #pragma unroll
    for (int off = 32; off; off >>= 1) s += __shfl_down(s, off);
    if (d == 0) dst[row] = sqrtf(s);
}

// ---------------------------------------------------------------------------
// Block reduction helpers (256 threads)
// ---------------------------------------------------------------------------
__device__ __forceinline__ float block_sum(float v, float* sh)
{
    #pragma unroll
    for (int off = 32; off; off >>= 1) v += __shfl_down(v, off);
    __syncthreads();
    if ((threadIdx.x & 63) == 0) sh[threadIdx.x >> 6] = v;
    __syncthreads();
    return sh[0] + sh[1] + sh[2] + sh[3];
}

__device__ __forceinline__ float block_max(float v, float* sh)
{
    #pragma unroll
    for (int off = 32; off; off >>= 1) v = fmaxf(v, __shfl_down(v, off));
    __syncthreads();
    if ((threadIdx.x & 63) == 0) sh[threadIdx.x >> 6] = v;
    __syncthreads();
    return fmaxf(fmaxf(sh[0], sh[1]), fmaxf(sh[2], sh[3]));
}

// ---------------------------------------------------------------------------
// Fused per-row pass: DCL terms + masked softmax. Writes fp32 attn in place
// and a bf16 copy for the AV MFMA GEMM. Contention-free partials (R1 win).
// Vectorized: float4/int4, thread t owns j = 4t..4t+3.
// ---------------------------------------------------------------------------
__global__ __launch_bounds__(256) void row_kernel(
    float* __restrict__ attnf, bf16_t* __restrict__ attnb,
    const int* __restrict__ mask,
    const float* __restrict__ qn, const float* __restrict__ kn,
    float* __restrict__ cl, float* __restrict__ rg)
{
    __shared__ float sh[4];
    const int row = blockIdx.x;            // bh*1024 + i
    const int bh = row >> 10, i = row & 1023;
    const int b = bh >> 3, h = bh & 7;
    const int t = threadIdx.x;
    float* srow = attnf + (size_t)row * NTOK;
    bf16_t* brow = attnb + (size_t)row * NTOK;
    const int* mrow = mask + ((size_t)b * NTOK + i) * NTOK;
    const float* knrow = kn + (size_t)bh * NTOK;
    const float qni = qn[row];

    float4 s4 = ((const float4*)srow)[t];
    int4  m4 = ((const int4*)mrow)[t];
    float4 kn4 = ((const float4*)knrow)[t];
    float s[4] = { s4.x, s4.y, s4.z, s4.w };
    int   m[4] = { m4.x, m4.y, m4.z, m4.w };
    float knv[4] = { kn4.x, kn4.y, kn4.z, kn4.w };

    float z[4];
    float pos = 0.f, alls = 0.f, zmax = -1e30f, reg = 0.f;
    #pragma unroll
    for (int u = 0; u < 4; ++u) {
        int j = t * 4 + u;
        float cosv = s[u] / (qni * knv[u]);
        float e = __expf(cosv * INV_TEMP);
        alls += e;
        if (m[u]) pos += e;
        reg += (float)m[u];
        if (j == i) reg -= 2.0f * (float)m[u];
        z[u] = (m[u] ? s[u] : -1.0e9f) * SCALE;
        zmax = fmaxf(zmax, z[u]);
    }
    float post = block_sum(pos, sh);
    float allt = block_sum(alls, sh);
    float regt = block_sum(reg, sh);
    float zmx  = block_max(zmax, sh);

    float ex[4], esum = 0.f;
    #pragma unroll
    for (int u = 0; u < 4; ++u) { ex[u] = __expf(z[u] - zmx); esum += ex[u]; }
    float est = block_sum(esum, sh);
    float inv = 1.0f / est;
    float4 o4 = { ex[0] * inv, ex[1] * inv, ex[2] * inv, ex[3] * inv };
    ((float4*)srow)[t] = o4;
    bf16x4 b4 = { (bf16_t)o4.x, (bf16_t)o4.y, (bf16_t)o4.z, (bf16_t)o4.w };
    ((bf16x4*)brow)[t] = b4;

    if (t == 0) {
        cl[row] = logf(allt) - logf(post);
        if (h == 0) rg[b * NTOK + i] = regt + 1.0f;
    }
}

// ---------------------------------------------------------------------------
// Single-block deterministic reduction of the DCL partials
// ---------------------------------------------------------------------------
__global__ __launch_bounds__(256) void finalize_kernel(
    const float* __restrict__ cl, const float* __restrict__ rg,
    float* __restrict__ dcl)
{
    __shared__ float sh[4];
    float s1 = 0.f, s2 = 0.f;
    for (int idx = threadIdx.x; idx < BH * NTOK; idx += 256) s1 += cl[idx];
    for (int idx = threadIdx.x; idx < BB * NTOK; idx += 256) s2 += rg[idx];
    s1 = block_sum(s1, sh);
    s2 = block_sum(s2, sh);
    if (threadIdx.x == 0) {
        dcl[0] = s1 * (1.0f / (float)(BB * HH * NTOK))
               + 0.3f * s2 * (1.0f / ((float)NTOK * (float)(NTOK - 1) * (float)BB));
    }
}

// ---------------------------------------------------------------------------
// AV: attnb[bh][1024,1024] @ vt[bh][64,1024]^T -> ctxb [b,n,h*64+d], TN=64
// ---------------------------------------------------------------------------
__global__ __launch_bounds__(256) void av_gemm(
    const bf16_t* __restrict__ attnb, const bf16_t* __restrict__ vt,
    bf16_t* __restrict__ ctxb)
{
    __shared__ __align__(16) bf16_t As[128 * 32];
    __shared__ __align__(16) bf16_t Bs[64 * 32];
    const int bh = blockIdx.z;
    const int b = bh >> 3, h = bh & 7;
    const int rowBase = blockIdx.y * 128;
    const bf16_t* A = attnb + (size_t)bh * NTOK * NTOK;
    const bf16_t* Bp = vt + (size_t)bh * DH * NTOK;

    f32x4 acc[2][4] = {};
    gemm_core<128, 64, 2, 4>(A + (size_t)rowBase * NTOK, NTOK,
                             Bp, NTOK, NTOK,
                             As, Bs, acc);

    const int l = threadIdx.x & 63, w = threadIdx.x >> 6;
    #pragma unroll
    for (int mt = 0; mt < 2; ++mt)
        #pragma unroll
        for (int nt = 0; nt < 4; ++nt)
            #pragma unroll
            for (int r = 0; r < 4; ++r) {
                int grow = rowBase + w * 32 + mt * 16 + (l >> 4) * 4 + r;
                int d = nt * 16 + (l & 15);
                ctxb[((size_t)b * NTOK + grow) * INNER + h * DH + d] = (bf16_t)acc[mt][nt][r];
            }
}

// ---------------------------------------------------------------------------
// Out projection: ctxb[4096,512] @ Wo_t^T + bo -> fp32 out
// ---------------------------------------------------------------------------
__global__ __launch_bounds__(256) void out_gemm(
    const bf16_t* __restrict__ ctxb, const bf16_t* __restrict__ wt,
    const float* __restrict__ bo, float* __restrict__ outp)
{
    __shared__ __align__(16) bf16_t As[128 * 32];
    __shared__ __align__(16) bf16_t Bs[128 * 32];
    const int rowBase = blockIdx.y * 128, colBase = blockIdx.x * 128;
    const bf16_t* Wot = wt + (size_t)3 * DIMD * INNER;

    f32x4 acc[4][4] = {};
    gemm_core<128, 128, 4, 4>(ctxb + (size_t)rowBase * INNER, INNER,
                              Wot + (size_t)colBase * INNER, INNER, INNER,
                              As, Bs, acc);

    const int l = threadIdx.x & 63, w = threadIdx.x >> 6;
    const int wm = w >> 1, wn = w & 1;
    #pragma unroll
    for (int mt = 0; mt < 4; ++mt)
        #pragma unroll
        for (int nt = 0; nt < 4; ++nt)
            #pragma unroll
            for (int r = 0; r < 4; ++r) {
                int grow = rowBase + wm * 64 + mt * 16 + (l >> 4) * 4 + r;
                int gcol = colBase + wn * 64 + nt * 16 + (l & 15);
                outp[(size_t)grow * DIMD + gcol] = acc[mt][nt][r] + bo[gcol];
            }
}

// ---------------------------------------------------------------------------
extern "C" void kernel_launch(void* const* d_in, const int* in_sizes, int n_in,
                              void* d_out, int out_size, void* d_ws, size_t ws_size,
                              hipStream_t stream)
{
    const float* x  = (const float*)d_in[0];
    const int* mask = (const int*)d_in[1];
    const float* Wq = (const float*)d_in[2];
    const float* bq = (const float*)d_in[3];
    const float* Wk = (const float*)d_in[4];
    const float* bk = (const float*)d_in[5];
    const float* Wv = (const float*)d_in[6];
    const float* bv = (const float*)d_in[7];
    const float* Wo = (const float*)d_in[8];
    const float* bo = (const float*)d_in[9];

    float* out   = (float*)d_out;                        // [4096, 512]
    float* attnf = out + (size_t)ROWS * DIMD;            // [32,1024,1024] fp32
    float* dcl   = attnf + (size_t)BH * NTOK * NTOK;     // scalar

    // ws layout (bf16 regions first, all 16B-aligned)
    char* wsb = (char*)d_ws;
    bf16_t* attnb = (bf16_t*)wsb;                              // 64 MB
    bf16_t* xb    = (bf16_t*)(wsb + (size_t)64 * 1024 * 1024); // 4 MB
    bf16_t* wt    = xb + (size_t)ROWS * DIMD;                  // 2 MB (4x 512x512)
    bf16_t* qb    = wt + (size_t)4 * DIMD * INNER;             // 4 MB
    bf16_t* kb    = qb + (size_t)BH * NTOK * DH;               // 4 MB
    bf16_t* vt    = kb + (size_t)BH * NTOK * DH;               // 4 MB
    bf16_t* ctxb  = vt + (size_t)BH * NTOK * DH;               // 4 MB
    float*  qn    = (float*)(ctxb + (size_t)ROWS * INNER);
    float*  kn    = qn + BH * NTOK;
    float*  cl    = kn + BH * NTOK;
    float*  rg    = cl + BH * NTOK;

    dim3 blk(256);
    convert_x<<<dim3(ROWS * DIMD / 1024), blk, 0, stream>>>(x, xb);
    transpose_w<<<dim3(16, 16, 4), blk, 0, stream>>>(Wq, Wk, Wv, Wo, wt);
    qkv_gemm<<<dim3(4, 32, 3), blk, 0, stream>>>(xb, wt, bq, bk, bv, qb, kb, vt);
    norm_kernel<<<dim3(BH * NTOK / 4, 2), blk, 0, stream>>>(qb, kb, qn, kn);
    scores_gemm<<<dim3(8, 8, 32), blk, 0, stream>>>(qb, kb, attnf);
    row_kernel<<<dim3(BH * NTOK), blk, 0, stream>>>(attnf, attnb, mask, qn, kn, cl, rg);
    finalize_kernel<<<1, blk, 0, stream>>>(cl, rg, dcl);
    av_gemm<<<dim3(1, 8, 32), blk, 0, stream>>>(attnb, vt, ctxb);
    out_gemm<<<dim3(4, 32), blk, 0, stream>>>(ctxb, wt, bo, out);
}